// Round 6
// baseline (173.454 us; speedup 1.0000x reference)
//
#include <hip/hip_runtime.h>
#include <stdint.h>

// Mask op: per row, top-5 intensity positions -> choose 2 via JAX threefry PRNG
// -> mask x at those positions with 1; emit masked tokens + positions padded to 5.
//
// Harness dtypes (confirmed by absmax decode r1/r2):
//   d_in[0] x:         int32 (reference int64 downgraded: x64 disabled)
//   d_in[1] intensity: float32
//   d_out:             int32
//
// PRNG: x64 DISABLED (x arrives int32) -> uniform is FLOAT32.
// jax_threefry_partitionable=True (default since 0.4.36):
//   counts = iota(u64, 5B); for g < 2^32: (b1,b2) = threefry2x32(key=(0,42), ctr=(0,g))
//   32-bit bits = b1 ^ b2   [JAX _threefry_random_bits_partitionable]
//   uniform order == (bits >> 9); stable argsort asc -> first 2.
// [threefry core verified vs Random123 KAT: key=(0,0),ctr=(0,0) -> 6b200159,99ba4efe]
//
// Outputs (concatenated in d_out, all int32):
//   [0, B*S)            mask_x
//   [B*S, B*S+5B)       mask_token (2 real + 3 zero pad)
//   [B*S+5B, B*S+10B)   mask_pos   (2 real + 3 zero pad)

#define S_LEN 1024
#define TOPK 5

__device__ __forceinline__ uint32_t rotl32(uint32_t x, int r) {
    return (x << r) | (x >> (32 - r));
}

// Exact JAX threefry2x32 (5x4 rounds, standard rotation schedule).
__device__ __forceinline__ void threefry2x32(uint32_t k0, uint32_t k1,
                                             uint32_t x0, uint32_t x1,
                                             uint32_t& o0, uint32_t& o1) {
    uint32_t ks2 = k0 ^ k1 ^ 0x1BD11BDAu;
    x0 += k0; x1 += k1;
#define TF_R4(a,b,c,d) \
    x0 += x1; x1 = rotl32(x1,a); x1 ^= x0; \
    x0 += x1; x1 = rotl32(x1,b); x1 ^= x0; \
    x0 += x1; x1 = rotl32(x1,c); x1 ^= x0; \
    x0 += x1; x1 = rotl32(x1,d); x1 ^= x0;
    TF_R4(13,15,26,6);   x0 += k1;  x1 += ks2 + 1u;
    TF_R4(17,29,16,24);  x0 += ks2; x1 += k0  + 2u;
    TF_R4(13,15,26,6);   x0 += k0;  x1 += k1  + 3u;
    TF_R4(17,29,16,24);  x0 += k1;  x1 += ks2 + 4u;
    TF_R4(13,15,26,6);   x0 += ks2; x1 += k0  + 5u;
#undef TF_R4
    o0 = x0; o1 = x1;
}

// compare-swap ensuring a >= b after call (descending order)
__device__ __forceinline__ void cswap_desc(uint64_t& a, uint64_t& b) {
    uint64_t lo = (a < b) ? a : b;
    uint64_t hi = (a < b) ? b : a;
    a = hi; b = lo;
}

__device__ __forceinline__ uint64_t u64max(uint64_t a, uint64_t b) {
    return (a > b) ? a : b;
}

__global__ __launch_bounds__(256)
void mask_kernel(const float* __restrict__ inten,
                 const int*   __restrict__ x,
                 int* __restrict__ out_x,
                 int* __restrict__ out_tok,
                 int* __restrict__ out_pos,
                 int B) {
    const int wave = threadIdx.x >> 6;
    const int lane = threadIdx.x & 63;
    const int row  = blockIdx.x * 4 + wave;
    if (row >= B) return;

    const float* irow = inten + (size_t)row * S_LEN;
    const int*   xrow = x     + (size_t)row * S_LEN;

    // ---- Pass 1: streaming local top-5 (desc by (value_bits, then lower index)) ----
    // key = (float_bits << 32) | (1023 - s). Intensity in [0,1) so bit pattern is
    // order-preserving; tie on value -> larger (1023-s) -> lower index wins (XLA top_k).
    uint64_t t0 = 0, t1 = 0, t2 = 0, t3 = 0, t4 = 0;
#pragma unroll
    for (int it = 0; it < 4; ++it) {
        const int sbase = it * 256 + lane * 4;
        const float4 v = *reinterpret_cast<const float4*>(irow + sbase);
#pragma unroll
        for (int q = 0; q < 4; ++q) {
            const float f = (q == 0) ? v.x : (q == 1) ? v.y : (q == 2) ? v.z : v.w;
            const uint32_t fb = __float_as_uint(f);
            const uint64_t key =
                ((uint64_t)fb << 32) | (uint32_t)(1023 - (sbase + q));
            // insert: only the tail slot can change, then bubble up
            t4 = u64max(t4, key);
            cswap_desc(t3, t4);
            cswap_desc(t2, t3);
            cswap_desc(t1, t2);
            cswap_desc(t0, t1);
        }
    }

    // ---- 5 rounds of wave-wide argmax-pop over each lane's sorted head ----
    int idx0 = 0, idx1 = 0, idx2 = 0, idx3 = 0, idx4 = 0;
#pragma unroll
    for (int r = 0; r < TOPK; ++r) {
        uint64_t w = t0;
#pragma unroll
        for (int off = 1; off < 64; off <<= 1) {
            const uint64_t o =
                (uint64_t)__shfl_xor((unsigned long long)w, off, 64);
            w = u64max(w, o);
        }
        // pop from the winning lane (keys are unique: index embedded)
        if (t0 == w) { t0 = t1; t1 = t2; t2 = t3; t3 = t4; t4 = 0; }
        const int s = 1023 - (int)((uint32_t)w & 1023u);
        if (r == 0) idx0 = s;
        else if (r == 1) idx1 = s;
        else if (r == 2) idx2 = s;
        else if (r == 3) idx3 = s;
        else idx4 = s;
    }

    // ---- JAX PRNG: f32 uniform, partitionable stream ----
    // bits[g] = b1 ^ b2 where (b1,b2) = threefry2x32((0,42), (0,g)); order by bits>>9.
    uint32_t kj = 0xFFFFFFFFu;
    if (lane < TOPK) {
        const uint32_t g = (uint32_t)row * 5u + (uint32_t)lane;
        uint32_t o0, o1;
        threefry2x32(0u, 42u, 0u, g, o0, o1);
        const uint32_t bits = o0 ^ o1;
        // uniform value order == (bits >> 9) order; stable tie-break by j
        kj = ((bits >> 9) << 3) | (uint32_t)lane;
    }
    const uint32_t q0 = __shfl(kj, 0, 64);
    const uint32_t q1 = __shfl(kj, 1, 64);
    const uint32_t q2 = __shfl(kj, 2, 64);
    const uint32_t q3 = __shfl(kj, 3, 64);
    const uint32_t q4 = __shfl(kj, 4, 64);

    const uint32_t mn1 = min(min(min(q0, q1), min(q2, q3)), q4);
    const int sel0 = (int)(mn1 & 7u);
    const uint32_t e0 = (q0 == mn1) ? 0xFFFFFFFFu : q0;
    const uint32_t e1 = (q1 == mn1) ? 0xFFFFFFFFu : q1;
    const uint32_t e2 = (q2 == mn1) ? 0xFFFFFFFFu : q2;
    const uint32_t e3 = (q3 == mn1) ? 0xFFFFFFFFu : q3;
    const uint32_t e4 = (q4 == mn1) ? 0xFFFFFFFFu : q4;
    const uint32_t mn2 = min(min(min(e0, e1), min(e2, e3)), e4);
    const int sel1 = (int)(mn2 & 7u);

    const int p0 = (sel0 == 0) ? idx0 : (sel0 == 1) ? idx1 : (sel0 == 2) ? idx2
                 : (sel0 == 3) ? idx3 : idx4;
    const int p1 = (sel1 == 0) ? idx0 : (sel1 == 1) ? idx1 : (sel1 == 2) ? idx2
                 : (sel1 == 3) ? idx3 : idx4;

    // ---- Pass 2: write mask_x (x with positions p0,p1 replaced by 1) ----
    int* orow = out_x + (size_t)row * S_LEN;
#pragma unroll
    for (int it = 0; it < 4; ++it) {
        const int sbase = it * 256 + lane * 4;
        int4 o = *reinterpret_cast<const int4*>(xrow + sbase);
        if (sbase + 0 == p0 || sbase + 0 == p1) o.x = 1;
        if (sbase + 1 == p0 || sbase + 1 == p1) o.y = 1;
        if (sbase + 2 == p0 || sbase + 2 == p1) o.z = 1;
        if (sbase + 3 == p0 || sbase + 3 == p1) o.w = 1;
        *reinterpret_cast<int4*>(orow + sbase) = o;
    }

    // ---- token / pos outputs (2 real + 3 zero pad each) ----
    if (lane == 0) {
        const int xa = xrow[p0];
        const int xb = xrow[p1];
        int* tk = out_tok + (size_t)row * 5;
        tk[0] = xa; tk[1] = xb; tk[2] = 0; tk[3] = 0; tk[4] = 0;
        int* pp = out_pos + (size_t)row * 5;
        pp[0] = p0; pp[1] = p1; pp[2] = 0; pp[3] = 0; pp[4] = 0;
    }
}

extern "C" void kernel_launch(void* const* d_in, const int* in_sizes, int n_in,
                              void* d_out, int out_size, void* d_ws, size_t ws_size,
                              hipStream_t stream) {
    const int*   x     = (const int*)d_in[0];
    const float* inten = (const float*)d_in[1];
    // d_in[2] is max_pred (=5); layout below assumes 5 (reference hardcodes LEN_MASK=2, pads to 5)

    const int BS = in_sizes[0];
    const int B  = BS / S_LEN;

    int* out     = (int*)d_out;
    int* out_tok = out + (size_t)B * S_LEN;
    int* out_pos = out_tok + (size_t)B * TOPK;

    dim3 grid((B + 3) / 4), block(256);
    hipLaunchKernelGGL(mask_kernel, grid, block, 0, stream,
                       inten, x, out, out_tok, out_pos, B);
}